// Round 4
// baseline (1933.809 us; speedup 1.0000x reference)
//
#include <hip/hip_runtime.h>
#include <hip/hip_bf16.h>
#include <math.h>

// NOVAE forward. Round 4:
//  - sinkhorn: 512 persistent blocks (2/CU), paired-row dot (shared x loads).
//    Discriminates latency-bound vs L3-BW-bound.
//  - decoder + coupling GEMMs: bf16 MFMA (16x16x32), weights pre-transposed
//    to [N][K] bf16. Encoder + cost GEMM stay fp32 (exponent amplification:
//    dK/K = 20*dM', so encoder errors are 10x amplified; decoder errors linear).

namespace {

constexpr float REG = 0.05f;
constexpr int SINK_ITERS = 200;
constexpr int NBLK = 512;                    // persistent grid: 2 blocks/CU
constexpr int NGRP = NBLK / 32;              // barrier groups of 32
constexpr float STOP_EPS = 3e-6f;

typedef __attribute__((ext_vector_type(8))) short bf16x8;
typedef __attribute__((ext_vector_type(4))) float f32x4;

__device__ __forceinline__ unsigned short f2bf(float f)
{
    return __hip_bfloat16_raw(__float2bfloat16(f)).x;
}

enum { EPI_BIAS_RELU = 0, EPI_BIAS = 1, EPI_COST = 2 };

// ---------------- fp32 tiled GEMM (encoder + cost matrix) ----------------
// A: MxK row-major. B: KxN row-major (BT=false) or NxK used as B^T (BT=true).
template<int EPI, bool BT>
__global__ __launch_bounds__(256)
void gemm_f32(const float* __restrict__ A, const float* __restrict__ Bm,
              const float* __restrict__ rb, const float* __restrict__ aux,
              float* __restrict__ C, float* __restrict__ maxOut,
              int M, int N, int K)
{
    constexpr int BM = 64, BNt = 64, BK = 16;
    __shared__ float sA[BK][BM + 4];
    __shared__ float sB[BK][BNt + 4];
    __shared__ float red[256];

    const int t  = threadIdx.x;
    const int tx = t & 15;
    const int ty = t >> 4;
    const int row0 = blockIdx.y * BM;
    const int col0 = blockIdx.x * BNt;

    const int lr = t >> 2;
    const int lc = (t & 3) << 2;

    float acc[4][4] = {};

    for (int k0 = 0; k0 < K; k0 += BK) {
        {
            const float4 a4 = *(const float4*)&A[(size_t)(row0 + lr) * K + k0 + lc];
            sA[lc + 0][lr] = a4.x; sA[lc + 1][lr] = a4.y;
            sA[lc + 2][lr] = a4.z; sA[lc + 3][lr] = a4.w;
        }
        if constexpr (!BT) {
            const int br = t >> 4, bc = (t & 15) << 2;
            const float4 b4 = *(const float4*)&Bm[(size_t)(k0 + br) * N + col0 + bc];
            *(float4*)&sB[br][bc] = b4;
        } else {
            const float4 b4 = *(const float4*)&Bm[(size_t)(col0 + lr) * K + k0 + lc];
            sB[lc + 0][lr] = b4.x; sB[lc + 1][lr] = b4.y;
            sB[lc + 2][lr] = b4.z; sB[lc + 3][lr] = b4.w;
        }
        __syncthreads();
        #pragma unroll
        for (int kk = 0; kk < BK; ++kk) {
            const float4 a4v = *(const float4*)&sA[kk][ty << 2];
            const float4 b4v = *(const float4*)&sB[kk][tx << 2];
            const float av[4] = {a4v.x, a4v.y, a4v.z, a4v.w};
            const float bv[4] = {b4v.x, b4v.y, b4v.z, b4v.w};
            #pragma unroll
            for (int i = 0; i < 4; ++i)
                #pragma unroll
                for (int j = 0; j < 4; ++j)
                    acc[i][j] = fmaf(av[i], bv[j], acc[i][j]);
        }
        __syncthreads();
    }

    if constexpr (EPI == EPI_COST) {
        float lmax = 0.0f;
        #pragma unroll
        for (int i = 0; i < 4; ++i) {
            const int r = row0 + (ty << 2) + i;
            const float znr = rb[r];
            #pragma unroll
            for (int j = 0; j < 4; ++j) {
                const int c = col0 + (tx << 2) + j;
                const float v = fmaxf(znr + aux[c] - 2.0f * acc[i][j], 0.0f);
                C[(size_t)r * N + c] = v;
                lmax = fmaxf(lmax, v);
            }
        }
        red[t] = lmax;
        __syncthreads();
        for (int s = 128; s > 0; s >>= 1) {
            if (t < s) red[t] = fmaxf(red[t], red[t + s]);
            __syncthreads();
        }
        if (t == 0) atomicMax((int*)maxOut, __float_as_int(red[0]));
    } else {
        #pragma unroll
        for (int i = 0; i < 4; ++i) {
            const int r = row0 + (ty << 2) + i;
            #pragma unroll
            for (int j = 0; j < 4; ++j) {
                const int c = col0 + (tx << 2) + j;
                float v = acc[i][j] + rb[c];
                if constexpr (EPI == EPI_BIAS_RELU) v = fmaxf(v, 0.0f);
                C[(size_t)r * N + c] = v;
            }
        }
    }
}

// ---------------- bf16 MFMA GEMM: C = A_bf16 @ Bt_bf16^T (+bias/relu/rowscale)
// A: [M][K] bf16 row-major. Bt: [N][K] bf16 row-major. 64x64 tile, BK=32,
// 256 thr = 4 waves; wave w owns rows w*16..w*16+15, all 64 cols (4 MFMA frags).
template<bool RELU, bool OUT_BF16, bool ROWSCALE>
__global__ __launch_bounds__(256)
void gemm_bf16_bt(const unsigned short* __restrict__ A,
                  const unsigned short* __restrict__ Bt,
                  const float* __restrict__ bias,
                  const float* __restrict__ rs,
                  void* __restrict__ C, int M, int N, int K)
{
    constexpr int BK = 32, LDK = 40;   // +8 shorts pad: <=2-way LDS banks
    __shared__ unsigned short sA[64 * LDK];
    __shared__ unsigned short sB[64 * LDK];
    const int t = threadIdx.x;
    const int w = t >> 6, l = t & 63;
    const int row0 = blockIdx.y * 64, col0 = blockIdx.x * 64;
    const int sr = t >> 2, sk = (t & 3) << 3;   // staging: row, k-offset (8 bf16)
    const int am = l & 15, aq = l >> 4;         // fragment coords

    f32x4 acc[4] = {};

    for (int k0 = 0; k0 < K; k0 += BK) {
        *(uint4*)&sA[sr * LDK + sk] = *(const uint4*)&A [(size_t)(row0 + sr) * K + k0 + sk];
        *(uint4*)&sB[sr * LDK + sk] = *(const uint4*)&Bt[(size_t)(col0 + sr) * K + k0 + sk];
        __syncthreads();
        const bf16x8 af = *(const bf16x8*)&sA[(w * 16 + am) * LDK + aq * 8];
        #pragma unroll
        for (int c = 0; c < 4; ++c) {
            const bf16x8 bfr = *(const bf16x8*)&sB[(c * 16 + am) * LDK + aq * 8];
            acc[c] = __builtin_amdgcn_mfma_f32_16x16x32_bf16(af, bfr, acc[c], 0, 0, 0);
        }
        __syncthreads();
    }

    // C/D layout (m89/m91 verified): col = lane&15, row = (lane>>4)*4 + reg
    #pragma unroll
    for (int c = 0; c < 4; ++c) {
        const int col = col0 + c * 16 + am;
        const float b = bias ? bias[col] : 0.0f;
        #pragma unroll
        for (int r = 0; r < 4; ++r) {
            const int row = row0 + w * 16 + aq * 4 + r;
            float v = acc[c][r] + b;
            if constexpr (RELU) v = fmaxf(v, 0.0f);
            if constexpr (ROWSCALE) v *= rs[row];
            if constexpr (OUT_BF16)
                ((unsigned short*)C)[(size_t)row * N + col] = f2bf(v);
            else
                ((float*)C)[(size_t)row * N + col] = v;
        }
    }
}

// transpose+cast: W [K][N] fp32 -> Wt [N][K] bf16 (32x32 LDS tiles)
__global__ __launch_bounds__(256)
void wtrans_k(const float* __restrict__ W, unsigned short* __restrict__ Wt,
              int K, int N)
{
    __shared__ float tile[32][33];
    const int tx  = threadIdx.x & 31;
    const int ty4 = threadIdx.x >> 5;
    const int k0 = blockIdx.y * 32, n0 = blockIdx.x * 32;
    #pragma unroll
    for (int r = 0; r < 4; ++r)
        tile[ty4 * 4 + r][tx] = W[(size_t)(k0 + ty4 * 4 + r) * N + n0 + tx];
    __syncthreads();
    #pragma unroll
    for (int r = 0; r < 4; ++r)
        Wt[(size_t)(n0 + ty4 * 4 + r) * K + k0 + tx] = f2bf(tile[tx][ty4 * 4 + r]);
}

// W2t[d][j] = bf16(v[j] * zp[j][d])  (transpose-cast of the v-scaled prior)
__global__ __launch_bounds__(256)
void vscale_t_k(const float* __restrict__ zp, const float* __restrict__ v,
                unsigned short* __restrict__ W2t)
{
    __shared__ float tile[32][33];
    const int tx  = threadIdx.x & 31;
    const int ty4 = threadIdx.x >> 5;
    const int j0 = blockIdx.y * 32, d0 = blockIdx.x * 32;
    #pragma unroll
    for (int r = 0; r < 4; ++r) {
        const int j = j0 + ty4 * 4 + r;
        tile[ty4 * 4 + r][tx] = v[j] * zp[(size_t)j * 128 + d0 + tx];
    }
    __syncthreads();
    #pragma unroll
    for (int r = 0; r < 4; ++r)
        W2t[(size_t)(d0 + ty4 * 4 + r) * 4096 + j0 + tx] = f2bf(tile[tx][ty4 * 4 + r]);
}

// squared L2 norm of each 128-wide row; one wave per row
__global__ __launch_bounds__(256)
void rownorm128_k(const float* __restrict__ X, float* __restrict__ out)
{
    const int row  = blockIdx.x * 4 + (threadIdx.x >> 6);
    const int lane = threadIdx.x & 63;
    const float2 v = ((const float2*)&X[(size_t)row * 128])[lane];
    float s = fmaf(v.x, v.x, v.y * v.y);
    #pragma unroll
    for (int o = 32; o > 0; o >>= 1) s += __shfl_down(s, o);
    if (lane == 0) out[row] = s;
}

// init u, v, max-scalar, early-stop slots, barrier state (ws poisoned 0xAA)
__global__ void init_k(float* __restrict__ u, float* __restrict__ v,
                       float* __restrict__ mx, int* __restrict__ dmax,
                       int* __restrict__ bar)
{
    const int i = blockIdx.x * 256 + threadIdx.x;
    if (i < 4096) { u[i] = 1.0f / 4096.0f; v[i] = 1.0f / 4096.0f; }
    if (i == 0) *mx = 0.0f;
    if (blockIdx.x == 0) {
        if (threadIdx.x < 32) dmax[threadIdx.x] = 0;
        else if (threadIdx.x < 64) bar[threadIdx.x - 32] = 0;
    }
}

// K = exp(-M/(reg*(maxM+1e-12))): bf16 K and bf16 K^T (LDS transpose)
__global__ __launch_bounds__(256)
void exp_transpose_k(const float* __restrict__ M,
                     unsigned short* __restrict__ Kb,
                     unsigned short* __restrict__ KTb,
                     const float* __restrict__ mx)
{
    __shared__ float tile[32][33];
    const float s = -1.0f / (REG * (*mx + 1e-12f));
    const int tx  = threadIdx.x & 31;
    const int ty4 = threadIdx.x >> 5;
    const int i0 = blockIdx.y * 32, j0 = blockIdx.x * 32;
    #pragma unroll
    for (int r = 0; r < 4; ++r) {
        const int i = i0 + ty4 * 4 + r;
        const size_t idx = (size_t)i * 4096 + j0 + tx;
        const float k = expf(M[idx] * s);
        Kb[idx] = f2bf(k);
        tile[ty4 * 4 + r][tx] = k;
    }
    __syncthreads();
    #pragma unroll
    for (int r = 0; r < 4; ++r)
        KTb[(size_t)(j0 + ty4 * 4 + r) * 4096 + i0 + tx] = f2bf(tile[tx][ty4 * 4 + r]);
}

// two-level grid barrier: NGRP groups of 32 blocks -> 1 global counter
__device__ __forceinline__
void grid_barrier(int* lcnt, int* gcnt, int* ggen)
{
    __syncthreads();
    if (threadIdx.x == 0) {
        __threadfence();
        const int gi = blockIdx.x & (NGRP - 1);
        const int g = __hip_atomic_load(ggen, __ATOMIC_RELAXED, __HIP_MEMORY_SCOPE_AGENT);
        if (__hip_atomic_fetch_add(&lcnt[gi], 1, __ATOMIC_ACQ_REL, __HIP_MEMORY_SCOPE_AGENT) == 31) {
            if (__hip_atomic_fetch_add(gcnt, 1, __ATOMIC_ACQ_REL, __HIP_MEMORY_SCOPE_AGENT) == NGRP - 1) {
                #pragma unroll
                for (int i = 0; i < NGRP; ++i)
                    __hip_atomic_store(&lcnt[i], 0, __ATOMIC_RELAXED, __HIP_MEMORY_SCOPE_AGENT);
                __hip_atomic_store(gcnt, 0, __ATOMIC_RELAXED, __HIP_MEMORY_SCOPE_AGENT);
                __hip_atomic_store(ggen, g + 1, __ATOMIC_RELEASE, __HIP_MEMORY_SCOPE_AGENT);
            } else {
                while (__hip_atomic_load(ggen, __ATOMIC_ACQUIRE, __HIP_MEMORY_SCOPE_AGENT) == g)
                    __builtin_amdgcn_s_sleep(1);
            }
        } else {
            while (__hip_atomic_load(ggen, __ATOMIC_ACQUIRE, __HIP_MEMORY_SCOPE_AGENT) == g)
                __builtin_amdgcn_s_sleep(1);
        }
        __threadfence();
    }
    __syncthreads();
}

// paired-row bf16 dot: two rows share the x-vector loads (64 B/lane/step)
__device__ __forceinline__
void row_dot2_bf16(const unsigned short* Mat, const float* x, int row, int lane,
                   float& o0, float& o1)
{
    const uint4*  a4 = (const uint4*)(Mat + (size_t)row * 4096);
    const uint4*  b4 = (const uint4*)(Mat + (size_t)(row + 1) * 4096);
    const float4* x4 = (const float4*)x;
    float s0 = 0, s1 = 0, t0 = 0, t1 = 0;
    #pragma unroll
    for (int w = 0; w < 8; ++w) {
        const int q = (w << 6) + lane;
        const uint4  ma = a4[q];
        const uint4  mb = b4[q];
        const float4 xa = x4[q * 2];
        const float4 xb = x4[q * 2 + 1];
        s0 = fmaf(__uint_as_float(ma.x << 16),         xa.x, s0);
        s1 = fmaf(__uint_as_float(ma.x & 0xffff0000u), xa.y, s1);
        s0 = fmaf(__uint_as_float(ma.y << 16),         xa.z, s0);
        s1 = fmaf(__uint_as_float(ma.y & 0xffff0000u), xa.w, s1);
        s0 = fmaf(__uint_as_float(ma.z << 16),         xb.x, s0);
        s1 = fmaf(__uint_as_float(ma.z & 0xffff0000u), xb.y, s1);
        s0 = fmaf(__uint_as_float(ma.w << 16),         xb.z, s0);
        s1 = fmaf(__uint_as_float(ma.w & 0xffff0000u), xb.w, s1);
        t0 = fmaf(__uint_as_float(mb.x << 16),         xa.x, t0);
        t1 = fmaf(__uint_as_float(mb.x & 0xffff0000u), xa.y, t1);
        t0 = fmaf(__uint_as_float(mb.y << 16),         xa.z, t0);
        t1 = fmaf(__uint_as_float(mb.y & 0xffff0000u), xa.w, t1);
        t0 = fmaf(__uint_as_float(mb.z << 16),         xb.x, t0);
        t1 = fmaf(__uint_as_float(mb.z & 0xffff0000u), xb.y, t1);
        t0 = fmaf(__uint_as_float(mb.w << 16),         xb.z, t0);
        t1 = fmaf(__uint_as_float(mb.w & 0xffff0000u), xb.w, t1);
    }
    float sa = s0 + s1, sb = t0 + t1;
    #pragma unroll
    for (int o = 32; o > 0; o >>= 1) {
        sa += __shfl_down(sa, o);
        sb += __shfl_down(sb, o);
    }
    o0 = sa; o1 = sb;
}

// Persistent Sinkhorn: 512 blocks (2/CU), 2 rows per wave
__global__ __launch_bounds__(256, 2)
void sinkhorn_k(const unsigned short* __restrict__ Kb,
                const unsigned short* __restrict__ KTb,
                float* __restrict__ u, float* __restrict__ v,
                int* __restrict__ dmax, int* __restrict__ bar)
{
    int* lcnt = bar;
    int* gcnt = bar + NGRP;
    int* ggen = bar + NGRP + 1;
    const int wv   = threadIdx.x >> 6;
    const int lane = threadIdx.x & 63;
    const int row0 = blockIdx.x * 8 + wv * 2;

    for (int it = 0; it < SINK_ITERS; ++it) {
        float s0, s1;
        // ---- v = (1/N) / (K^T u)
        row_dot2_bf16(KTb, u, row0, lane, s0, s1);
        if (lane == 0) {
            v[row0]     = (1.0f / 4096.0f) / s0;
            v[row0 + 1] = (1.0f / 4096.0f) / s1;
        }
        grid_barrier(lcnt, gcnt, ggen);

        // ---- u = (1/N) / (K v), sample convergence every 8 iters
        const bool chk = ((it & 7) == 7);
        row_dot2_bf16(Kb, v, row0, lane, s0, s1);
        if (lane == 0) {
            const float nu0 = (1.0f / 4096.0f) / s0;
            const float nu1 = (1.0f / 4096.0f) / s1;
            if (chk) {
                const float ou0 = u[row0], ou1 = u[row0 + 1];
                const float d0 = fabsf(nu0 - ou0) / (fabsf(ou0) + 1e-37f);
                const float d1 = fabsf(nu1 - ou1) / (fabsf(ou1) + 1e-37f);
                atomicMax(&dmax[it >> 3], __float_as_int(fmaxf(d0, d1)));
            }
            u[row0] = nu0; u[row0 + 1] = nu1;
        }
        grid_barrier(lcnt, gcnt, ggen);

        if (chk) {
            const float dm = __int_as_float(
                __hip_atomic_load(&dmax[it >> 3], __ATOMIC_RELAXED, __HIP_MEMORY_SCOPE_AGENT));
            if (dm < STOP_EPS) break;
        }
    }
}

} // namespace

extern "C" void kernel_launch(void* const* d_in, const int* in_sizes, int n_in,
                              void* d_out, int out_size, void* d_ws, size_t ws_size,
                              hipStream_t stream)
{
    const float* x  = (const float*)d_in[0];
    const float* zp = (const float*)d_in[1];
    const float* ew[4] = {(const float*)d_in[2],  (const float*)d_in[4],
                          (const float*)d_in[6],  (const float*)d_in[8]};
    const float* eb[4] = {(const float*)d_in[3],  (const float*)d_in[5],
                          (const float*)d_in[7],  (const float*)d_in[9]};
    const float* dw[4] = {(const float*)d_in[10], (const float*)d_in[12],
                          (const float*)d_in[14], (const float*)d_in[16]};
    const float* db[4] = {(const float*)d_in[11], (const float*)d_in[13],
                          (const float*)d_in[15], (const float*)d_in[17]};
    float* out = (float*)d_out;

    char* w = (char*)d_ws;
    size_t off = 0;
    auto alloc = [&](size_t bytes) {
        void* p = (void*)(w + off);
        off += (bytes + 255) & ~size_t(255);
        return p;
    };
    float* Mm = (float*)alloc((size_t)4096 * 4096 * 4);   // cost matrix (fp32)
    unsigned short* Kb  = (unsigned short*)alloc((size_t)4096 * 4096 * 2);
    unsigned short* KTb = (unsigned short*)alloc((size_t)4096 * 4096 * 2);
    float* a0   = (float*)alloc((size_t)4096 * 1024 * 4);
    float* a1   = (float*)alloc((size_t)4096 * 1024 * 4);
    float* a2   = (float*)alloc((size_t)4096 * 512 * 4);
    float* z_   = (float*)alloc((size_t)4096 * 128 * 4);
    float* zn   = (float*)alloc(4096 * 4);
    float* pn   = (float*)alloc(4096 * 4);
    float* u    = (float*)alloc(4096 * 4);
    float* v    = (float*)alloc(4096 * 4);
    float* mx   = (float*)alloc(256);
    int*   dmax = (int*)alloc(32 * 4);
    int*   bar  = (int*)alloc(32 * 4);
    (void)ws_size; (void)in_sizes; (void)n_in; (void)out_size;

    // bf16 decoder-side buffers aliased into Mm (dead after exp_transpose_k)
    {
        char* m = (char*)Mm;
        size_t o2 = 0;
        auto alias = [&](size_t bytes) {
            void* p = (void*)(m + o2);
            o2 += (bytes + 255) & ~size_t(255);
            return p;
        };
        (void)alias; // layout below
    }
    char* m = (char*)Mm;
    unsigned short* zselb = (unsigned short*)(m);                        // 1 MB
    unsigned short* a0b   = (unsigned short*)(m + (1u << 20));           // 4 MB
    unsigned short* a1b   = (unsigned short*)(m + (5u << 20));           // 8 MB
    unsigned short* a2b   = (unsigned short*)(m + (13u << 20));          // 4 MB
    unsigned short* W2t   = (unsigned short*)(m + (17u << 20));          // 1 MB
    unsigned short* dwt0  = (unsigned short*)(m + (18u << 20));          // 128 KB
    unsigned short* dwt1  = (unsigned short*)(m + (19u << 20));          // 1 MB
    unsigned short* dwt2  = (unsigned short*)(m + (20u << 20));          // 1 MB
    unsigned short* dwt3  = (unsigned short*)(m + (21u << 20));          // 1 MB

    const dim3 blk(256);

    // ---- encoder (fp32): 1024 -> 512 -> 1024 -> 512 -> 128
    gemm_f32<EPI_BIAS_RELU,false><<<dim3(512/64,  4096/64), blk, 0, stream>>>(x,  ew[0], eb[0], nullptr, a0, nullptr, 4096, 512, 1024);
    gemm_f32<EPI_BIAS_RELU,false><<<dim3(1024/64, 4096/64), blk, 0, stream>>>(a0, ew[1], eb[1], nullptr, a1, nullptr, 4096, 1024, 512);
    gemm_f32<EPI_BIAS_RELU,false><<<dim3(512/64,  4096/64), blk, 0, stream>>>(a1, ew[2], eb[2], nullptr, a2, nullptr, 4096, 512, 1024);
    gemm_f32<EPI_BIAS,     false><<<dim3(128/64,  4096/64), blk, 0, stream>>>(a2, ew[3], eb[3], nullptr, z_, nullptr, 4096, 128, 512);

    // ---- cost matrix + bf16 K / K^T
    rownorm128_k<<<1024, blk, 0, stream>>>(z_, zn);
    rownorm128_k<<<1024, blk, 0, stream>>>(zp, pn);
    init_k<<<16, blk, 0, stream>>>(u, v, mx, dmax, bar);

    gemm_f32<EPI_COST,true><<<dim3(64, 64), blk, 0, stream>>>(z_, zp, zn, pn, Mm, mx, 4096, 4096, 128);
    exp_transpose_k<<<dim3(128, 128), blk, 0, stream>>>(Mm, Kb, KTb, mx);
    // Mm is dead from here on; its space now holds the bf16 decoder buffers.

    // ---- decoder weight transpose+cast (after exp_transpose: aliased space)
    wtrans_k<<<dim3(512/32,  128/32),  blk, 0, stream>>>(dw[0], dwt0, 128,  512);
    wtrans_k<<<dim3(1024/32, 512/32),  blk, 0, stream>>>(dw[1], dwt1, 512,  1024);
    wtrans_k<<<dim3(512/32,  1024/32), blk, 0, stream>>>(dw[2], dwt2, 1024, 512);
    wtrans_k<<<dim3(1024/32, 512/32),  blk, 0, stream>>>(dw[3], dwt3, 512,  1024);

    // ---- Sinkhorn: one persistent dispatch (512 blocks, 2/CU)
    sinkhorn_k<<<NBLK, blk, 0, stream>>>(Kb, KTb, u, v, dmax, bar);

    // ---- z_sel = diag(u) * K * (diag(v) * zp)   via bf16 MFMA
    vscale_t_k<<<dim3(128/32, 4096/32), blk, 0, stream>>>(zp, v, W2t);
    gemm_bf16_bt<false,true,true><<<dim3(128/64, 4096/64), blk, 0, stream>>>(Kb, W2t, nullptr, u, zselb, 4096, 128, 4096);

    // ---- decoder (bf16 MFMA): 128 -> 512 -> 1024 -> 512 -> 1024
    gemm_bf16_bt<true, true, false><<<dim3(512/64,  4096/64), blk, 0, stream>>>(zselb, dwt0, db[0], nullptr, a0b, 4096, 512, 128);
    gemm_bf16_bt<true, true, false><<<dim3(1024/64, 4096/64), blk, 0, stream>>>(a0b,   dwt1, db[1], nullptr, a1b, 4096, 1024, 512);
    gemm_bf16_bt<true, true, false><<<dim3(512/64,  4096/64), blk, 0, stream>>>(a1b,   dwt2, db[2], nullptr, a2b, 4096, 512, 1024);
    gemm_bf16_bt<false,false,false><<<dim3(1024/64, 4096/64), blk, 0, stream>>>(a2b,   dwt3, db[3], nullptr, out, 4096, 1024, 512);
}

// Round 5
// 1487.309 us; speedup vs baseline: 1.3002x; 1.3002x over previous
//
#include <hip/hip_runtime.h>
#include <hip/hip_bf16.h>
#include <math.h>

// NOVAE forward. Round 5:
//  - sinkhorn: reverted verbatim to R3 winner (256 blocks, 4 rows/wave) —
//    R4 proved it sits on the Infinity-Cache BW roofline (~17 TB/s).
//  - encoder L0-L2 + cost GEMM: split-bf16x2 MFMA (3 products hi*hi+lo*hi+hi*lo,
//    rel err ~4e-6 -> exponent-safe) on a 128x128-tile kernel.
//  - encoder L3 (N=128): fp32 VALU GEMM reading hi/lo activations.
//  - decoder + coupling: plain bf16 MFMA (R4, proven).

namespace {

constexpr float REG = 0.05f;
constexpr int SINK_ITERS = 200;
constexpr int NBLK = 256;                       // sinkhorn persistent grid: 1 block/CU
constexpr int NGRP = NBLK / 32;                 // barrier groups
constexpr int ROWS_PER_WAVE = 4096 / NBLK / 4;  // 4 rows per wave
constexpr float STOP_EPS = 3e-6f;

typedef __attribute__((ext_vector_type(8))) short bf16x8;
typedef __attribute__((ext_vector_type(4))) float f32x4;

__device__ __forceinline__ unsigned short f2bf(float f)
{
    return __hip_bfloat16_raw(__float2bfloat16(f)).x;
}
__device__ __forceinline__ float bf2f(unsigned short u)
{
    return __uint_as_float(((unsigned int)u) << 16);
}

enum { EPI_SPLIT_RELU = 0, EPI_COST = 1 };

// ---------- 128x128 split-bf16x2 MFMA GEMM: C = (Ah+Al) @ (Bh+Bl)^T ----------
// A: [M][K] bf16 hi/lo. Bt: [N][K] bf16 hi/lo. 256 thr = 4 waves, each wave a
// 64x64 quadrant (4x4 frags of 16x16x32). 3 MFMA per frag-pair (skip lo*lo).
template<int EPI>
__global__ __launch_bounds__(256)
void gemm128_split(const unsigned short* __restrict__ Ah,
                   const unsigned short* __restrict__ Al,
                   const unsigned short* __restrict__ Bh,
                   const unsigned short* __restrict__ Bl,
                   const float* __restrict__ rb,    // bias[col] | zn[row]
                   const float* __restrict__ aux,   // pn[col] (COST)
                   void* __restrict__ C0,           // hi-out | fp32 M
                   unsigned short* __restrict__ C1, // lo-out
                   float* __restrict__ maxOut,
                   int M, int N, int K)
{
    constexpr int LDK = 40;     // +8 shorts pad, 16B-aligned rows
    __shared__ unsigned short sAh[128 * LDK], sAl[128 * LDK];
    __shared__ unsigned short sBh[128 * LDK], sBl[128 * LDK];
    __shared__ float red[256];

    const int t = threadIdx.x;
    const int w = t >> 6, lane = t & 63;
    const int wr = (w >> 1) * 64, wc = (w & 1) * 64;
    const int am = lane & 15, aq = lane >> 4;
    const int row0 = blockIdx.y * 128, col0 = blockIdx.x * 128;
    const int sr0 = t >> 2, sc = (t & 3) << 3;

    f32x4 acc[4][4] = {};

    for (int k0 = 0; k0 < K; k0 += 32) {
        #pragma unroll
        for (int p = 0; p < 2; ++p) {
            const int r = sr0 + p * 64;
            const size_t ga = (size_t)(row0 + r) * K + k0 + sc;
            const size_t gb = (size_t)(col0 + r) * K + k0 + sc;
            *(uint4*)&sAh[r * LDK + sc] = *(const uint4*)&Ah[ga];
            *(uint4*)&sAl[r * LDK + sc] = *(const uint4*)&Al[ga];
            *(uint4*)&sBh[r * LDK + sc] = *(const uint4*)&Bh[gb];
            *(uint4*)&sBl[r * LDK + sc] = *(const uint4*)&Bl[gb];
        }
        __syncthreads();
        bf16x8 ah[4], al[4], bh[4], bl[4];
        #pragma unroll
        for (int i = 0; i < 4; ++i) {
            const int ra = (wr + i * 16 + am) * LDK + aq * 8;
            const int rbx = (wc + i * 16 + am) * LDK + aq * 8;
            ah[i] = *(const bf16x8*)&sAh[ra];
            al[i] = *(const bf16x8*)&sAl[ra];
            bh[i] = *(const bf16x8*)&sBh[rbx];
            bl[i] = *(const bf16x8*)&sBl[rbx];
        }
        #pragma unroll
        for (int i = 0; i < 4; ++i)
            #pragma unroll
            for (int j = 0; j < 4; ++j) {
                acc[i][j] = __builtin_amdgcn_mfma_f32_16x16x32_bf16(ah[i], bh[j], acc[i][j], 0, 0, 0);
                acc[i][j] = __builtin_amdgcn_mfma_f32_16x16x32_bf16(al[i], bh[j], acc[i][j], 0, 0, 0);
                acc[i][j] = __builtin_amdgcn_mfma_f32_16x16x32_bf16(ah[i], bl[j], acc[i][j], 0, 0, 0);
            }
        __syncthreads();
    }

    // C/D layout: col = lane&15, row = (lane>>4)*4 + reg  (m89/m91 verified)
    if constexpr (EPI == EPI_COST) {
        float lmax = 0.0f;
        #pragma unroll
        for (int i = 0; i < 4; ++i) {
            #pragma unroll
            for (int r = 0; r < 4; ++r) {
                const int row = row0 + wr + i * 16 + aq * 4 + r;
                const float znr = rb[row];
                #pragma unroll
                for (int j = 0; j < 4; ++j) {
                    const int col = col0 + wc + j * 16 + am;
                    const float v = fmaxf(znr + aux[col] - 2.0f * acc[i][j][r], 0.0f);
                    ((float*)C0)[(size_t)row * N + col] = v;
                    lmax = fmaxf(lmax, v);
                }
            }
        }
        red[t] = lmax;
        __syncthreads();
        for (int s = 128; s > 0; s >>= 1) {
            if (t < s) red[t] = fmaxf(red[t], red[t + s]);
            __syncthreads();
        }
        if (t == 0) atomicMax((int*)maxOut, __float_as_int(red[0]));
    } else {
        #pragma unroll
        for (int j = 0; j < 4; ++j) {
            const int col = col0 + wc + j * 16 + am;
            const float b = rb[col];
            #pragma unroll
            for (int i = 0; i < 4; ++i)
                #pragma unroll
                for (int r = 0; r < 4; ++r) {
                    const int row = row0 + wr + i * 16 + aq * 4 + r;
                    const float v = fmaxf(acc[i][j][r] + b, 0.0f);
                    const unsigned short hi = f2bf(v);
                    ((unsigned short*)C0)[(size_t)row * N + col] = hi;
                    C1[(size_t)row * N + col] = f2bf(v - bf2f(hi));
                }
        }
    }
}

// ---------- fp32 GEMM, A from hi/lo bf16 pair (encoder L3, N=128) ----------
__global__ __launch_bounds__(256)
void gemm_f32_hl(const unsigned short* __restrict__ Ah,
                 const unsigned short* __restrict__ Al,
                 const float* __restrict__ B, const float* __restrict__ bias,
                 float* __restrict__ C, int M, int N, int K)
{
    constexpr int BM = 64, BNt = 64, BK = 16;
    __shared__ float sA[BK][BM + 4];
    __shared__ float sB[BK][BNt + 4];
    const int t = threadIdx.x;
    const int tx = t & 15, ty = t >> 4;
    const int row0 = blockIdx.y * BM, col0 = blockIdx.x * BNt;
    const int lr = t >> 2, lc = (t & 3) << 2;

    float acc[4][4] = {};
    for (int k0 = 0; k0 < K; k0 += BK) {
        {
            const size_t ga = (size_t)(row0 + lr) * K + k0 + lc;
            const uint2 h2 = *(const uint2*)&Ah[ga];
            const uint2 l2 = *(const uint2*)&Al[ga];
            sA[lc + 0][lr] = __uint_as_float(h2.x << 16)          + __uint_as_float(l2.x << 16);
            sA[lc + 1][lr] = __uint_as_float(h2.x & 0xffff0000u)  + __uint_as_float(l2.x & 0xffff0000u);
            sA[lc + 2][lr] = __uint_as_float(h2.y << 16)          + __uint_as_float(l2.y << 16);
            sA[lc + 3][lr] = __uint_as_float(h2.y & 0xffff0000u)  + __uint_as_float(l2.y & 0xffff0000u);
        }
        {
            const int br = t >> 4, bc = (t & 15) << 2;
            const float4 b4 = *(const float4*)&B[(size_t)(k0 + br) * N + col0 + bc];
            *(float4*)&sB[br][bc] = b4;
        }
        __syncthreads();
        #pragma unroll
        for (int kk = 0; kk < BK; ++kk) {
            const float4 a4v = *(const float4*)&sA[kk][ty << 2];
            const float4 b4v = *(const float4*)&sB[kk][tx << 2];
            const float av[4] = {a4v.x, a4v.y, a4v.z, a4v.w};
            const float bv[4] = {b4v.x, b4v.y, b4v.z, b4v.w};
            #pragma unroll
            for (int i = 0; i < 4; ++i)
                #pragma unroll
                for (int j = 0; j < 4; ++j)
                    acc[i][j] = fmaf(av[i], bv[j], acc[i][j]);
        }
        __syncthreads();
    }
    #pragma unroll
    for (int i = 0; i < 4; ++i) {
        const int r = row0 + (ty << 2) + i;
        #pragma unroll
        for (int j = 0; j < 4; ++j) {
            const int c = col0 + (tx << 2) + j;
            C[(size_t)r * N + c] = acc[i][j] + bias[c];
        }
    }
}

// ---------- plain bf16 MFMA GEMM (decoder + coupling), 64x64 tile (R4) ----------
template<bool RELU, bool OUT_BF16, bool ROWSCALE>
__global__ __launch_bounds__(256)
void gemm_bf16_bt(const unsigned short* __restrict__ A,
                  const unsigned short* __restrict__ Bt,
                  const float* __restrict__ bias,
                  const float* __restrict__ rs,
                  void* __restrict__ C, int M, int N, int K)
{
    constexpr int BK = 32, LDK = 40;
    __shared__ unsigned short sA[64 * LDK];
    __shared__ unsigned short sB[64 * LDK];
    const int t = threadIdx.x;
    const int w = t >> 6, l = t & 63;
    const int row0 = blockIdx.y * 64, col0 = blockIdx.x * 64;
    const int sr = t >> 2, sk = (t & 3) << 3;
    const int am = l & 15, aq = l >> 4;

    f32x4 acc[4] = {};
    for (int k0 = 0; k0 < K; k0 += BK) {
        *(uint4*)&sA[sr * LDK + sk] = *(const uint4*)&A [(size_t)(row0 + sr) * K + k0 + sk];
        *(uint4*)&sB[sr * LDK + sk] = *(const uint4*)&Bt[(size_t)(col0 + sr) * K + k0 + sk];
        __syncthreads();
        const bf16x8 af = *(const bf16x8*)&sA[(w * 16 + am) * LDK + aq * 8];
        #pragma unroll
        for (int c = 0; c < 4; ++c) {
            const bf16x8 bfr = *(const bf16x8*)&sB[(c * 16 + am) * LDK + aq * 8];
            acc[c] = __builtin_amdgcn_mfma_f32_16x16x32_bf16(af, bfr, acc[c], 0, 0, 0);
        }
        __syncthreads();
    }
    #pragma unroll
    for (int c = 0; c < 4; ++c) {
        const int col = col0 + c * 16 + am;
        const float b = bias ? bias[col] : 0.0f;
        #pragma unroll
        for (int r = 0; r < 4; ++r) {
            const int row = row0 + w * 16 + aq * 4 + r;
            float v = acc[c][r] + b;
            if constexpr (RELU) v = fmaxf(v, 0.0f);
            if constexpr (ROWSCALE) v *= rs[row];
            if constexpr (OUT_BF16)
                ((unsigned short*)C)[(size_t)row * N + col] = f2bf(v);
            else
                ((float*)C)[(size_t)row * N + col] = v;
        }
    }
}

// ---------- small prep kernels ----------
// split fp32 -> bf16 hi/lo, 4 elems/thread
__global__ __launch_bounds__(256)
void split_k(const float* __restrict__ x, unsigned short* __restrict__ hi,
             unsigned short* __restrict__ lo)
{
    const int i4 = (blockIdx.x * 256 + threadIdx.x) * 4;
    const float4 v = *(const float4*)&x[i4];
    const float vv[4] = {v.x, v.y, v.z, v.w};
    unsigned short h[4], l[4];
    #pragma unroll
    for (int k = 0; k < 4; ++k) {
        h[k] = f2bf(vv[k]);
        l[k] = f2bf(vv[k] - bf2f(h[k]));
    }
    *(uint2*)&hi[i4] = *(uint2*)h;
    *(uint2*)&lo[i4] = *(uint2*)l;
}

// transpose+cast: W [K][N] fp32 -> Wt [N][K] bf16 (plain)
__global__ __launch_bounds__(256)
void wtrans_k(const float* __restrict__ W, unsigned short* __restrict__ Wt,
              int K, int N)
{
    __shared__ float tile[32][33];
    const int tx = threadIdx.x & 31, ty4 = threadIdx.x >> 5;
    const int k0 = blockIdx.y * 32, n0 = blockIdx.x * 32;
    #pragma unroll
    for (int r = 0; r < 4; ++r)
        tile[ty4 * 4 + r][tx] = W[(size_t)(k0 + ty4 * 4 + r) * N + n0 + tx];
    __syncthreads();
    #pragma unroll
    for (int r = 0; r < 4; ++r)
        Wt[(size_t)(n0 + ty4 * 4 + r) * K + k0 + tx] = f2bf(tile[tx][ty4 * 4 + r]);
}

// transpose+split-cast: W [K][N] fp32 -> Wt_hi/Wt_lo [N][K] bf16
__global__ __launch_bounds__(256)
void wtrans_split_k(const float* __restrict__ W, unsigned short* __restrict__ Wth,
                    unsigned short* __restrict__ Wtl, int K, int N)
{
    __shared__ float tile[32][33];
    const int tx = threadIdx.x & 31, ty4 = threadIdx.x >> 5;
    const int k0 = blockIdx.y * 32, n0 = blockIdx.x * 32;
    #pragma unroll
    for (int r = 0; r < 4; ++r)
        tile[ty4 * 4 + r][tx] = W[(size_t)(k0 + ty4 * 4 + r) * N + n0 + tx];
    __syncthreads();
    #pragma unroll
    for (int r = 0; r < 4; ++r) {
        const float v = tile[tx][ty4 * 4 + r];
        const unsigned short h = f2bf(v);
        const size_t idx = (size_t)(n0 + ty4 * 4 + r) * K + k0 + tx;
        Wth[idx] = h;
        Wtl[idx] = f2bf(v - bf2f(h));
    }
}

// W2t[d][j] = bf16(v[j] * zp[j][d])
__global__ __launch_bounds__(256)
void vscale_t_k(const float* __restrict__ zp, const float* __restrict__ v,
                unsigned short* __restrict__ W2t)
{
    __shared__ float tile[32][33];
    const int tx = threadIdx.x & 31, ty4 = threadIdx.x >> 5;
    const int j0 = blockIdx.y * 32, d0 = blockIdx.x * 32;
    #pragma unroll
    for (int r = 0; r < 4; ++r) {
        const int j = j0 + ty4 * 4 + r;
        tile[ty4 * 4 + r][tx] = v[j] * zp[(size_t)j * 128 + d0 + tx];
    }
    __syncthreads();
    #pragma unroll
    for (int r = 0; r < 4; ++r)
        W2t[(size_t)(d0 + ty4 * 4 + r) * 4096 + j0 + tx] = f2bf(tile[tx][ty4 * 4 + r]);
}

__global__ __launch_bounds__(256)
void rownorm128_k(const float* __restrict__ X, float* __restrict__ out)
{
    const int row = blockIdx.x * 4 + (threadIdx.x >> 6);
    const int lane = threadIdx.x & 63;
    const float2 v = ((const float2*)&X[(size_t)row * 128])[lane];
    float s = fmaf(v.x, v.x, v.y * v.y);
    #pragma unroll
    for (int o = 32; o > 0; o >>= 1) s += __shfl_down(s, o);
    if (lane == 0) out[row] = s;
}

__global__ void init_k(float* __restrict__ u, float* __restrict__ v,
                       float* __restrict__ mx, int* __restrict__ dmax,
                       int* __restrict__ bar)
{
    const int i = blockIdx.x * 256 + threadIdx.x;
    if (i < 4096) { u[i] = 1.0f / 4096.0f; v[i] = 1.0f / 4096.0f; }
    if (i == 0) *mx = 0.0f;
    if (blockIdx.x == 0) {
        if (threadIdx.x < 32) dmax[threadIdx.x] = 0;
        else if (threadIdx.x < 64) bar[threadIdx.x - 32] = 0;
    }
}

// K = exp(-M/(reg*(maxM+1e-12))): bf16 K and bf16 K^T
__global__ __launch_bounds__(256)
void exp_transpose_k(const float* __restrict__ M,
                     unsigned short* __restrict__ Kb,
                     unsigned short* __restrict__ KTb,
                     const float* __restrict__ mx)
{
    __shared__ float tile[32][33];
    const float s = -1.0f / (REG * (*mx + 1e-12f));
    const int tx = threadIdx.x & 31, ty4 = threadIdx.x >> 5;
    const int i0 = blockIdx.y * 32, j0 = blockIdx.x * 32;
    #pragma unroll
    for (int r = 0; r < 4; ++r) {
        const int i = i0 + ty4 * 4 + r;
        const size_t idx = (size_t)i * 4096 + j0 + tx;
        const float k = expf(M[idx] * s);
        Kb[idx] = f2bf(k);
        tile[ty4 * 4 + r][tx] = k;
    }
    __syncthreads();
    #pragma unroll
    for (int r = 0; r < 4; ++r)
        KTb[(size_t)(j0 + ty4 * 4 + r) * 4096 + i0 + tx] = f2bf(tile[tx][ty4 * 4 + r]);
}

// ---------- Sinkhorn (R3 winner, verbatim structure) ----------
__device__ __forceinline__
void grid_barrier(int* lcnt, int* gcnt, int* ggen)
{
    __syncthreads();
    if (threadIdx.x == 0) {
        __threadfence();
        const int gi = blockIdx.x & (NGRP - 1);
        const int g = __hip_atomic_load(ggen, __ATOMIC_RELAXED, __HIP_MEMORY_SCOPE_AGENT);
        if (__hip_atomic_fetch_add(&lcnt[gi], 1, __ATOMIC_ACQ_REL, __HIP_MEMORY_SCOPE_AGENT) == 31) {
            if (__hip_atomic_fetch_add(gcnt, 1, __ATOMIC_ACQ_REL, __HIP_MEMORY_SCOPE_AGENT) == NGRP - 1) {
                #pragma unroll
                for (int i = 0; i < NGRP; ++i)
                    __hip_atomic_store(&lcnt[i], 0, __ATOMIC_RELAXED, __HIP_MEMORY_SCOPE_AGENT);
                __hip_atomic_store(gcnt, 0, __ATOMIC_RELAXED, __HIP_MEMORY_SCOPE_AGENT);
                __hip_atomic_store(ggen, g + 1, __ATOMIC_RELEASE, __HIP_MEMORY_SCOPE_AGENT);
            } else {
                while (__hip_atomic_load(ggen, __ATOMIC_ACQUIRE, __HIP_MEMORY_SCOPE_AGENT) == g)
                    __builtin_amdgcn_s_sleep(1);
            }
        } else {
            while (__hip_atomic_load(ggen, __ATOMIC_ACQUIRE, __HIP_MEMORY_SCOPE_AGENT) == g)
                __builtin_amdgcn_s_sleep(1);
        }
        __threadfence();
    }
    __syncthreads();
}

__device__ __forceinline__
float row_dot_bf16(const unsigned short* Mat, const float* x, int row, int lane)
{
    const uint4*  m4 = (const uint4*)(Mat + (size_t)row * 4096);
    const float4* x4 = (const float4*)x;
    float s0 = 0, s1 = 0, s2 = 0, s3 = 0;
    #pragma unroll
    for (int w = 0; w < 8; ++w) {
        const int q = (w << 6) + lane;
        const uint4  m  = m4[q];
        const float4 xa = x4[q * 2];
        const float4 xb = x4[q * 2 + 1];
        s0 = fmaf(__uint_as_float(m.x << 16),          xa.x, s0);
        s1 = fmaf(__uint_as_float(m.x & 0xffff0000u),  xa.y, s1);
        s2 = fmaf(__uint_as_float(m.y << 16),          xa.z, s2);
        s3 = fmaf(__uint_as_float(m.y & 0xffff0000u),  xa.w, s3);
        s0 = fmaf(__uint_as_float(m.z << 16),          xb.x, s0);
        s1 = fmaf(__uint_as_float(m.z & 0xffff0000u),  xb.y, s1);
        s2 = fmaf(__uint_as_float(m.w << 16),          xb.z, s2);
        s3 = fmaf(__uint_as_float(m.w & 0xffff0000u),  xb.w, s3);
    }
    float s = (s0 + s1) + (s2 + s3);
    #pragma unroll
    for (int o = 32; o > 0; o >>= 1) s += __shfl_down(s, o);
    return s;
}

__global__ __launch_bounds__(256, 1)
void sinkhorn_k(const unsigned short* __restrict__ Kb,
                const unsigned short* __restrict__ KTb,
                float* __restrict__ u, float* __restrict__ v,
                int* __restrict__ dmax, int* __restrict__ bar)
{
    int* lcnt = bar;
    int* gcnt = bar + NGRP;
    int* ggen = bar + NGRP + 1;
    const int wv   = threadIdx.x >> 6;
    const int lane = threadIdx.x & 63;
    const int row0 = blockIdx.x * (ROWS_PER_WAVE * 4) + wv * ROWS_PER_WAVE;

    for (int it = 0; it < SINK_ITERS; ++it) {
        #pragma unroll
        for (int rr = 0; rr < ROWS_PER_WAVE; ++rr) {
            const int row = row0 + rr;
            const float s = row_dot_bf16(KTb, u, row, lane);
            if (lane == 0) v[row] = (1.0f / 4096.0f) / s;
        }
        grid_barrier(lcnt, gcnt, ggen);

        const bool chk = ((it & 7) == 7);
        #pragma unroll
        for (int rr = 0; rr < ROWS_PER_WAVE; ++rr) {
            const int row = row0 + rr;
            const float s = row_dot_bf16(Kb, v, row, lane);
            if (lane == 0) {
                const float nu = (1.0f / 4096.0f) / s;
                if (chk) {
                    const float ou = u[row];
                    const float d = fabsf(nu - ou) / (fabsf(ou) + 1e-37f);
                    atomicMax(&dmax[it >> 3], __float_as_int(d));
                }
                u[row] = nu;
            }
        }
        grid_barrier(lcnt, gcnt, ggen);

        if (chk) {
            const float dm = __int_as_float(
                __hip_atomic_load(&dmax[it >> 3], __ATOMIC_RELAXED, __HIP_MEMORY_SCOPE_AGENT));
            if (dm < STOP_EPS) break;
        }
    }
}

} // namespace

extern "C" void kernel_launch(void* const* d_in, const int* in_sizes, int n_in,
                              void* d_out, int out_size, void* d_ws, size_t ws_size,
                              hipStream_t stream)
{
    const float* x  = (const float*)d_in[0];
    const float* zp = (const float*)d_in[1];
    const float* ew[4] = {(const float*)d_in[2],  (const float*)d_in[4],
                          (const float*)d_in[6],  (const float*)d_in[8]};
    const float* eb[4] = {(const float*)d_in[3],  (const float*)d_in[5],
                          (const float*)d_in[7],  (const float*)d_in[9]};
    const float* dw[4] = {(const float*)d_in[10], (const float*)d_in[12],
                          (const float*)d_in[14], (const float*)d_in[16]};
    const float* db[4] = {(const float*)d_in[11], (const float*)d_in[13],
                          (const float*)d_in[15], (const float*)d_in[17]};
    float* out = (float*)d_out;

    char* w = (char*)d_ws;
    size_t off = 0;
    auto alloc = [&](size_t bytes) {
        void* p = (void*)(w + off);
        off += (bytes + 255) & ~size_t(255);
        return p;
    };
    float* Mm = (float*)alloc((size_t)4096 * 4096 * 4);                 // 64 MiB
    unsigned short* Kb  = (unsigned short*)alloc((size_t)4096 * 4096 * 2);
    unsigned short* KTb = (unsigned short*)alloc((size_t)4096 * 4096 * 2);
    float* z_  = (float*)alloc((size_t)4096 * 128 * 4);
    unsigned short* zh  = (unsigned short*)alloc((size_t)4096 * 128 * 2);
    unsigned short* zl  = (unsigned short*)alloc((size_t)4096 * 128 * 2);
    unsigned short* zph = (unsigned short*)alloc((size_t)4096 * 128 * 2);
    unsigned short* zpl = (unsigned short*)alloc((size_t)4096 * 128 * 2);
    float* zn   = (float*)alloc(4096 * 4);
    float* pn   = (float*)alloc(4096 * 4);
    float* u    = (float*)alloc(4096 * 4);
    float* v    = (float*)alloc(4096 * 4);
    float* mx   = (float*)alloc(256);
    int*   dmax = (int*)alloc(32 * 4);
    int*   bar  = (int*)alloc(32 * 4);
    (void)ws_size; (void)in_sizes; (void)n_in; (void)out_size;

    // --- encoder-phase aliases inside Mm (dead before cost GEMM writes Mm)
    char* m = (char*)Mm;
    unsigned short* w0th = (unsigned short*)(m + (size_t)0  * (1u << 20));
    unsigned short* w0tl = (unsigned short*)(m + (size_t)1  * (1u << 20));
    unsigned short* w1th = (unsigned short*)(m + (size_t)2  * (1u << 20));
    unsigned short* w1tl = (unsigned short*)(m + (size_t)3  * (1u << 20));
    unsigned short* w2th = (unsigned short*)(m + (size_t)4  * (1u << 20));
    unsigned short* w2tl = (unsigned short*)(m + (size_t)5  * (1u << 20));
    unsigned short* a0h  = (unsigned short*)(m + (size_t)6  * (1u << 20));
    unsigned short* a0l  = (unsigned short*)(m + (size_t)10 * (1u << 20));
    unsigned short* a1h  = (unsigned short*)(m + (size_t)14 * (1u << 20));
    unsigned short* a1l  = (unsigned short*)(m + (size_t)22 * (1u << 20));
    unsigned short* a2h  = (unsigned short*)(m + (size_t)30 * (1u << 20));
    unsigned short* a2l  = (unsigned short*)(m + (size_t)34 * (1u << 20));  // ends 38 MiB
    // --- x splits inside Kb region (dead after L0; Kb written after encoder)
    unsigned short* xh = (unsigned short*)Kb;
    unsigned short* xl = (unsigned short*)((char*)Kb + ((size_t)8 << 20));
    // --- decoder-phase aliases inside Mm (dead after exp_transpose)
    unsigned short* zselb = (unsigned short*)(m);
    unsigned short* a0b   = (unsigned short*)(m + (1u << 20));
    unsigned short* a1b   = (unsigned short*)(m + (5u << 20));
    unsigned short* a2b   = (unsigned short*)(m + (13u << 20));
    unsigned short* W2t   = (unsigned short*)(m + (17u << 20));
    unsigned short* dwt0  = (unsigned short*)(m + (18u << 20));
    unsigned short* dwt1  = (unsigned short*)(m + (19u << 20));
    unsigned short* dwt2  = (unsigned short*)(m + (20u << 20));
    unsigned short* dwt3  = (unsigned short*)(m + (21u << 20));

    const dim3 blk(256);

    // ---- prep: splits + encoder weight transposes
    split_k<<<4096, blk, 0, stream>>>(x, xh, xl);                 // 4096x1024
    split_k<<<512,  blk, 0, stream>>>(zp, zph, zpl);              // 4096x128
    wtrans_split_k<<<dim3(512/32, 1024/32), blk, 0, stream>>>(ew[0], w0th, w0tl, 1024, 512);
    wtrans_split_k<<<dim3(1024/32, 512/32), blk, 0, stream>>>(ew[1], w1th, w1tl, 512, 1024);
    wtrans_split_k<<<dim3(512/32, 1024/32), blk, 0, stream>>>(ew[2], w2th, w2tl, 1024, 512);
    rownorm128_k<<<1024, blk, 0, stream>>>(zp, pn);
    init_k<<<16, blk, 0, stream>>>(u, v, mx, dmax, bar);

    // ---- encoder: 1024 -> 512 -> 1024 -> 512 -> 128 (split-bf16x2 MFMA)
    gemm128_split<EPI_SPLIT_RELU><<<dim3(512/128,  4096/128), blk, 0, stream>>>(xh,  xl,  w0th, w0tl, eb[0], nullptr, a0h, a0l, nullptr, 4096, 512, 1024);
    gemm128_split<EPI_SPLIT_RELU><<<dim3(1024/128, 4096/128), blk, 0, stream>>>(a0h, a0l, w1th, w1tl, eb[1], nullptr, a1h, a1l, nullptr, 4096, 1024, 512);
    gemm128_split<EPI_SPLIT_RELU><<<dim3(512/128,  4096/128), blk, 0, stream>>>(a1h, a1l, w2th, w2tl, eb[2], nullptr, a2h, a2l, nullptr, 4096, 512, 1024);
    gemm_f32_hl<<<dim3(128/64, 4096/64), blk, 0, stream>>>(a2h, a2l, ew[3], eb[3], z_, 4096, 128, 512);

    // ---- cost matrix (split MFMA) + bf16 K / K^T
    rownorm128_k<<<1024, blk, 0, stream>>>(z_, zn);
    split_k<<<512, blk, 0, stream>>>(z_, zh, zl);
    gemm128_split<EPI_COST><<<dim3(4096/128, 4096/128), blk, 0, stream>>>(zh, zl, zph, zpl, zn, pn, Mm, nullptr, mx, 4096, 4096, 128);
    exp_transpose_k<<<dim3(128, 128), blk, 0, stream>>>(Mm, Kb, KTb, mx);
    // Mm dead; region reused for decoder-phase bf16 buffers.

    // ---- decoder weight transpose+cast
    wtrans_k<<<dim3(512/32,  128/32),  blk, 0, stream>>>(dw[0], dwt0, 128,  512);
    wtrans_k<<<dim3(1024/32, 512/32),  blk, 0, stream>>>(dw[1], dwt1, 512,  1024);
    wtrans_k<<<dim3(512/32,  1024/32), blk, 0, stream>>>(dw[2], dwt2, 1024, 512);
    wtrans_k<<<dim3(1024/32, 512/32),  blk, 0, stream>>>(dw[3], dwt3, 512,  1024);

    // ---- Sinkhorn: one persistent dispatch (R3 config)
    sinkhorn_k<<<NBLK, blk, 0, stream>>>(Kb, KTb, u, v, dmax, bar);

    // ---- z_sel = diag(u) * K * (diag(v) * zp)   via bf16 MFMA
    vscale_t_k<<<dim3(128/32, 4096/32), blk, 0, stream>>>(zp, v, W2t);
    gemm_bf16_bt<false,true,true><<<dim3(128/64, 4096/64), blk, 0, stream>>>(Kb, W2t, nullptr, u, zselb, 4096, 128, 4096);

    // ---- decoder (bf16 MFMA): 128 -> 512 -> 1024 -> 512 -> 1024
    gemm_bf16_bt<true, true, false><<<dim3(512/64,  4096/64), blk, 0, stream>>>(zselb, dwt0, db[0], nullptr, a0b, 4096, 512, 128);
    gemm_bf16_bt<true, true, false><<<dim3(1024/64, 4096/64), blk, 0, stream>>>(a0b,   dwt1, db[1], nullptr, a1b, 4096, 1024, 512);
    gemm_bf16_bt<true, true, false><<<dim3(512/64,  4096/64), blk, 0, stream>>>(a1b,   dwt2, db[2], nullptr, a2b, 4096, 512, 1024);
    gemm_bf16_bt<false,false,false><<<dim3(1024/64, 4096/64), blk, 0, stream>>>(a2b,   dwt3, db[3], nullptr, out, 4096, 1024, 512);
}